// Round 2
// baseline (60.269 us; speedup 1.0000x reference)
//
#include <hip/hip_runtime.h>
#include <hip/hip_bf16.h>
#include <cstdint>

#define LL 256   // L
#define NN 512   // N
#define DD 256   // D
#define HH 8
#define EPSF 1e-5f

typedef __attribute__((ext_vector_type(8))) __bf16 bf16x8;
typedef __attribute__((ext_vector_type(4))) float f32x4;

static __device__ __forceinline__ unsigned short f2bf(float f) {
    unsigned int u = __float_as_uint(f);
    u = (u + 0x7FFFu + ((u >> 16) & 1u)) >> 16;   // RNE
    return (unsigned short)u;
}

// K0: per-l: LN(msa[0,0,l,:]) -> q[l,h,d] -> Wt[l,h,c] = sum_d q*Wk (bf16, h padded to 16)
__global__ __launch_bounds__(256) void k_prep(
    const float* __restrict__ msa, const float* __restrict__ Wq,
    const float* __restrict__ bq, const float* __restrict__ Wk,
    const float* __restrict__ gamma, const float* __restrict__ beta,
    unsigned short* __restrict__ Wt)
{
    const int l = blockIdx.x, t = threadIdx.x;
    __shared__ float lnx[DD];
    __shared__ float qv[DD];
    __shared__ float red[8];
    float x = msa[(size_t)l * DD + t];          // msa[0][0][l][t]
    float s = x, ss = x * x;
    #pragma unroll
    for (int m = 32; m >= 1; m >>= 1) { s += __shfl_xor(s, m); ss += __shfl_xor(ss, m); }
    const int wv = t >> 6;
    if ((t & 63) == 0) { red[wv * 2] = s; red[wv * 2 + 1] = ss; }
    __syncthreads();
    s  = red[0] + red[2] + red[4] + red[6];
    ss = red[1] + red[3] + red[5] + red[7];
    float mean = s * (1.f / DD);
    float var  = ss * (1.f / DD) - mean * mean;
    float rs   = rsqrtf(var + EPSF);
    lnx[t] = (x - mean) * rs * gamma[t] + beta[t];
    __syncthreads();
    float acc = bq[t];
    const float4* wr = (const float4*)(Wq + (size_t)t * DD);
    #pragma unroll 4
    for (int j = 0; j < DD / 4; ++j) {
        float4 w4 = wr[j];
        acc += lnx[4*j]*w4.x + lnx[4*j+1]*w4.y + lnx[4*j+2]*w4.z + lnx[4*j+3]*w4.w;
    }
    qv[t] = acc * 0.17677669529663687f;        // 1/sqrt(32)
    __syncthreads();
    #pragma unroll
    for (int h = 0; h < HH; ++h) {
        float a = 0.f;
        #pragma unroll 8
        for (int d = 0; d < 32; ++d)
            a += qv[h * 32 + d] * Wk[(size_t)(h * 32 + d) * DD + t];
        Wt[((size_t)l * 16 + h) * DD + t] = f2bf(a);
    }
    #pragma unroll
    for (int h = HH; h < 16; ++h) Wt[((size_t)l * 16 + h) * DD + t] = 0;
}

// K1: block per l. Stream 512 rows: LN -> bf16 swizzled LDS -> MFMA vs Wt frags ->
// logits[8][512] -> softmax over n -> fp32 out.
__global__ __launch_bounds__(512) void k_main(
    const float* __restrict__ msa, const unsigned short* __restrict__ Wt,
    const float* __restrict__ gamma, const float* __restrict__ beta,
    float* __restrict__ out)
{
    const int l = blockIdx.x;
    const int tid = threadIdx.x, wave = tid >> 6, lane = tid & 63;
    __shared__ __align__(16) unsigned long long Abuf[128 * 64];  // 64 KB bf16 A-tile (swizzled)
    __shared__ __align__(16) float logits[HH * NN];              // [h][n] 16 KB
    __shared__ float stats[16];

    float4 gg = *(const float4*)(gamma + lane * 4);
    float4 bt = *(const float4*)(beta  + lane * 4);

    const int col = lane & 15, kb = lane >> 4;
    bf16x8 bfr[8];
    {
        const unsigned short* wp = Wt + ((size_t)l * 16 + col) * DD + kb * 8;
        #pragma unroll
        for (int ks = 0; ks < 8; ++ks)
            bfr[ks] = *(const bf16x8*)(wp + ks * 32);
    }

    for (int tile = 0; tile < 4; ++tile) {
        #pragma unroll
        for (int half = 0; half < 2; ++half) {
            float4 v[8];
            #pragma unroll
            for (int r = 0; r < 8; ++r) {
                int n = tile * 128 + wave * 16 + half * 8 + r;
                v[r] = *((const float4*)(msa + ((size_t)n * LL + l) * DD) + lane);
            }
            #pragma unroll
            for (int r = 0; r < 8; ++r) {
                int rowL = wave * 16 + half * 8 + r;
                float s  = v[r].x + v[r].y + v[r].z + v[r].w;
                float ss = v[r].x*v[r].x + v[r].y*v[r].y + v[r].z*v[r].z + v[r].w*v[r].w;
                #pragma unroll
                for (int m = 32; m >= 1; m >>= 1) { s += __shfl_xor(s, m); ss += __shfl_xor(ss, m); }
                float mean = s * (1.f / DD), var = ss * (1.f / DD) - mean * mean;
                float rs = rsqrtf(var + EPSF);
                float y0 = (v[r].x - mean) * rs * gg.x + bt.x;
                float y1 = (v[r].y - mean) * rs * gg.y + bt.y;
                float y2 = (v[r].z - mean) * rs * gg.z + bt.z;
                float y3 = (v[r].w - mean) * rs * gg.w + bt.w;
                unsigned long long pk =
                      (unsigned long long)f2bf(y0)
                    | ((unsigned long long)f2bf(y1) << 16)
                    | ((unsigned long long)f2bf(y2) << 32)
                    | ((unsigned long long)f2bf(y3) << 48);
                int byte = rowL * 512 + ((lane * 8) ^ ((rowL & 7) << 4));
                *(unsigned long long*)((char*)Abuf + byte) = pk;
            }
        }
        __syncthreads();
        f32x4 acc = {0.f, 0.f, 0.f, 0.f};
        const int row = wave * 16 + col;
        #pragma unroll
        for (int ks = 0; ks < 8; ++ks) {
            int byte = row * 512 + ((ks * 64 + kb * 16) ^ ((row & 7) << 4));
            bf16x8 a = *(const bf16x8*)((const char*)Abuf + byte);
            acc = __builtin_amdgcn_mfma_f32_16x16x32_bf16(a, bfr[ks], acc, 0, 0, 0);
        }
        if (col < HH) {
            #pragma unroll
            for (int i = 0; i < 4; ++i) {
                int n = tile * 128 + wave * 16 + kb * 4 + i;   // C/D: row=(lane>>4)*4+i, col=lane&15
                logits[col * NN + n] = acc[i];
            }
        }
        __syncthreads();
    }

    {   // softmax stats: wave w -> head h=w
        const float* lp = logits + wave * NN;
        const float4* l4 = (const float4*)lp + lane * 2;
        float4 aa = l4[0], bb = l4[1];
        float x0[8] = {aa.x, aa.y, aa.z, aa.w, bb.x, bb.y, bb.z, bb.w};
        float mx = x0[0];
        #pragma unroll
        for (int i = 1; i < 8; ++i) mx = fmaxf(mx, x0[i]);
        #pragma unroll
        for (int m = 32; m >= 1; m >>= 1) mx = fmaxf(mx, __shfl_xor(mx, m));
        float sm = 0.f;
        #pragma unroll
        for (int i = 0; i < 8; ++i) sm += __expf(x0[i] - mx);
        #pragma unroll
        for (int m = 32; m >= 1; m >>= 1) sm += __shfl_xor(sm, m);
        if (lane == 0) { stats[wave] = mx; stats[8 + wave] = 1.f / sm; }
    }
    __syncthreads();
    {   // write: thread t -> n=t, all 8 heads, two float4 stores (fp32 output!)
        int n = tid;
        float o[8];
        #pragma unroll
        for (int h = 0; h < HH; ++h)
            o[h] = __expf(logits[h * NN + n] - stats[h]) * stats[8 + h];
        float* op = out + (size_t)n * LL * HH + (size_t)l * HH;
        float4 p0 = {o[0], o[1], o[2], o[3]};
        float4 p1 = {o[4], o[5], o[6], o[7]};
        *(float4*)(op)     = p0;
        *(float4*)(op + 4) = p1;
    }
}

extern "C" void kernel_launch(void* const* d_in, const int* in_sizes, int n_in,
                              void* d_out, int out_size, void* d_ws, size_t ws_size,
                              hipStream_t stream) {
    (void)in_sizes; (void)n_in; (void)out_size; (void)ws_size;
    const float* msa   = (const float*)d_in[0];
    const float* Wq    = (const float*)d_in[1];
    const float* bq    = (const float*)d_in[2];
    const float* Wk    = (const float*)d_in[3];
    // d_in[4] = bk: adds a per-(l,h) constant to logits -> cancelled by softmax over n.
    const float* gamma = (const float*)d_in[5];
    const float* beta  = (const float*)d_in[6];
    unsigned short* Wt = (unsigned short*)d_ws;          // [256][16][256] bf16 = 2 MB
    k_prep<<<dim3(LL), dim3(256), 0, stream>>>(msa, Wq, bq, Wk, gamma, beta, Wt);
    k_main<<<dim3(LL), dim3(512), 0, stream>>>(msa, Wt, gamma, beta, (float*)d_out);
}

// Round 3
// 53.653 us; speedup vs baseline: 1.1233x; 1.1233x over previous
//
#include <hip/hip_runtime.h>
#include <hip/hip_bf16.h>
#include <cstdint>

#define LL 256   // L
#define NN 512   // N
#define DD 256   // D
#define HH 8
#define EPSF 1e-5f

typedef __attribute__((ext_vector_type(8))) __bf16 bf16x8;
typedef __attribute__((ext_vector_type(8))) unsigned short u16x8;
typedef __attribute__((ext_vector_type(4))) float f32x4;

static __device__ __forceinline__ unsigned short f2bf(float f) {
    unsigned int u = __float_as_uint(f);
    u = (u + 0x7FFFu + ((u >> 16) & 1u)) >> 16;   // RNE
    return (unsigned short)u;
}

// K0: per-l: LN(msa[0,0,l,:]) -> q -> Wg[l,h,c] = gamma[c] * sum_d q[h,d]*Wk[h*32+d,c]
// (bf16, 16 cols: 8 heads, col8 = ones, cols 9-15 = 0), plus G[l,h] = sum_c Wg.
__global__ __launch_bounds__(256) void k_prep(
    const float* __restrict__ msa, const float* __restrict__ Wq,
    const float* __restrict__ bq, const float* __restrict__ Wk,
    const float* __restrict__ gamma, const float* __restrict__ beta,
    unsigned short* __restrict__ Wg, float* __restrict__ Gout)
{
    const int l = blockIdx.x, t = threadIdx.x;
    const int wv = t >> 6, lane = t & 63;
    __shared__ float lnx[DD];
    __shared__ float qv[DD];
    __shared__ float red[8];
    __shared__ float Gpart[HH][4];
    float x = msa[(size_t)l * DD + t];          // msa[0][0][l][t]
    float s = x, ss = x * x;
    #pragma unroll
    for (int m = 32; m >= 1; m >>= 1) { s += __shfl_xor(s, m); ss += __shfl_xor(ss, m); }
    if (lane == 0) { red[wv * 2] = s; red[wv * 2 + 1] = ss; }
    __syncthreads();
    s  = red[0] + red[2] + red[4] + red[6];
    ss = red[1] + red[3] + red[5] + red[7];
    float mean = s * (1.f / DD);
    float var  = ss * (1.f / DD) - mean * mean;
    float rs   = rsqrtf(var + EPSF);
    lnx[t] = (x - mean) * rs * gamma[t] + beta[t];
    __syncthreads();
    float acc = bq[t];
    const float4* wr = (const float4*)(Wq + (size_t)t * DD);
    #pragma unroll 4
    for (int j = 0; j < DD / 4; ++j) {
        float4 w4 = wr[j];
        acc += lnx[4*j]*w4.x + lnx[4*j+1]*w4.y + lnx[4*j+2]*w4.z + lnx[4*j+3]*w4.w;
    }
    qv[t] = acc * 0.17677669529663687f;        // 1/sqrt(32)
    __syncthreads();
    const float gm = gamma[t];
    #pragma unroll
    for (int h = 0; h < HH; ++h) {
        float a = 0.f;
        #pragma unroll 8
        for (int d = 0; d < 32; ++d)
            a += qv[h * 32 + d] * Wk[(size_t)(h * 32 + d) * DD + t];
        unsigned short w = f2bf(gm * a);
        Wg[((size_t)l * 16 + h) * DD + t] = w;
        float gw = __uint_as_float((unsigned)w << 16);
        #pragma unroll
        for (int m = 32; m >= 1; m >>= 1) gw += __shfl_xor(gw, m);
        if (lane == 0) Gpart[h][wv] = gw;
    }
    Wg[((size_t)l * 16 + 8) * DD + t] = 0x3F80;   // ones column -> row sum of x
    #pragma unroll
    for (int h = HH + 1; h < 16; ++h) Wg[((size_t)l * 16 + h) * DD + t] = 0;
    __syncthreads();
    if (t < HH) Gout[(size_t)l * HH + t] = Gpart[t][0] + Gpart[t][1] + Gpart[t][2] + Gpart[t][3];
}

// K1: block per l. Raw-x MFMA direct from global (A-fragment-layout loads, no LDS staging).
// Row stats via ones-column (Sx) and Gram diagonal (Sx^2). Softmax fix-up in epilogue.
__global__ __launch_bounds__(512) void k_main(
    const float* __restrict__ msa, const unsigned short* __restrict__ Wg,
    const float* __restrict__ Gsum, float* __restrict__ out)
{
    const int l = blockIdx.x;
    const int tid = threadIdx.x, wave = tid >> 6, lane = tid & 63;
    __shared__ __align__(16) float logits[HH * NN];   // raw dots Σ x·(γW̃)  [h][n] 16 KB
    __shared__ __align__(16) float sS[NN];            // Σx per row
    __shared__ __align__(16) float sQ[NN];            // Σx² per row
    __shared__ float stats[16];
    __shared__ float Gs[HH];
    if (tid < HH) Gs[tid] = Gsum[(size_t)l * HH + tid];

    const int col = lane & 15, kb = lane >> 4;
    bf16x8 bfr[8];
    {
        const unsigned short* wp = Wg + ((size_t)l * 16 + col) * DD + kb * 8;
        #pragma unroll
        for (int ks = 0; ks < 8; ++ks)
            bfr[ks] = *(const bf16x8*)(wp + ks * 32);
    }

    #pragma unroll 1
    for (int g = 0; g < 4; ++g) {
        // A-fragment-layout load: lane holds row (lane&15), k = ks*32 + kb*8 + j
        const int nb = (g << 7) + (wave << 4);
        const float* rp = msa + ((size_t)(nb + col) * LL + l) * DD + (kb << 3);
        float4 v0[8], v1[8];
        #pragma unroll
        for (int ks = 0; ks < 8; ++ks) {
            v0[ks] = *(const float4*)(rp + ks * 32);
            v1[ks] = *(const float4*)(rp + ks * 32 + 4);
        }
        f32x4 hacc = {0.f, 0.f, 0.f, 0.f};
        f32x4 gacc = {0.f, 0.f, 0.f, 0.f};
        #pragma unroll
        for (int ks = 0; ks < 8; ++ks) {
            u16x8 au;
            au[0] = f2bf(v0[ks].x); au[1] = f2bf(v0[ks].y);
            au[2] = f2bf(v0[ks].z); au[3] = f2bf(v0[ks].w);
            au[4] = f2bf(v1[ks].x); au[5] = f2bf(v1[ks].y);
            au[6] = f2bf(v1[ks].z); au[7] = f2bf(v1[ks].w);
            bf16x8 a = __builtin_bit_cast(bf16x8, au);
            hacc = __builtin_amdgcn_mfma_f32_16x16x32_bf16(a, bfr[ks], hacc, 0, 0, 0);
            gacc = __builtin_amdgcn_mfma_f32_16x16x32_bf16(a, a,        gacc, 0, 0, 0);
        }
        // C/D layout: col = lane&15, row = kb*4 + i
        #pragma unroll
        for (int i = 0; i < 4; ++i) {
            int n = nb + (kb << 2) + i;
            if (col < HH)       logits[col * NN + n] = hacc[i];
            else if (col == HH) sS[n] = hacc[i];
        }
        if (kb == (col >> 2)) sQ[nb + col] = gacc[col & 3];   // Gram diagonal
    }
    __syncthreads();

    {   // softmax stats: wave w -> head h=w; adjust logits on the fly
        const int h = wave;
        const float Gh = Gs[h];
        const float* lp = logits + h * NN;
        float4 ra = ((const float4*)lp)[lane * 2];
        float4 rb = ((const float4*)lp)[lane * 2 + 1];
        float4 sa = ((const float4*)sS)[lane * 2];
        float4 sb = ((const float4*)sS)[lane * 2 + 1];
        float4 qa = ((const float4*)sQ)[lane * 2];
        float4 qb = ((const float4*)sQ)[lane * 2 + 1];
        float raw[8] = {ra.x, ra.y, ra.z, ra.w, rb.x, rb.y, rb.z, rb.w};
        float sv[8]  = {sa.x, sa.y, sa.z, sa.w, sb.x, sb.y, sb.z, sb.w};
        float qv2[8] = {qa.x, qa.y, qa.z, qa.w, qb.x, qb.y, qb.z, qb.w};
        float adj[8];
        #pragma unroll
        for (int i = 0; i < 8; ++i) {
            float mean = sv[i] * (1.f / DD);
            float var  = qv2[i] * (1.f / DD) - mean * mean;
            float rs   = rsqrtf(var + EPSF);
            adj[i] = rs * (raw[i] - mean * Gh);
        }
        float mx = adj[0];
        #pragma unroll
        for (int i = 1; i < 8; ++i) mx = fmaxf(mx, adj[i]);
        #pragma unroll
        for (int m = 32; m >= 1; m >>= 1) mx = fmaxf(mx, __shfl_xor(mx, m));
        float sm = 0.f;
        #pragma unroll
        for (int i = 0; i < 8; ++i) sm += __expf(adj[i] - mx);
        #pragma unroll
        for (int m = 32; m >= 1; m >>= 1) sm += __shfl_xor(sm, m);
        if (lane == 0) { stats[wave] = mx; stats[8 + wave] = 1.f / sm; }
    }
    __syncthreads();

    {   // write: thread t -> n=t, all 8 heads, fp32 out
        const int n = tid;
        float s = sS[n], q2 = sQ[n];
        float mean = s * (1.f / DD);
        float var  = q2 * (1.f / DD) - mean * mean;
        float rs   = rsqrtf(var + EPSF);
        float o[8];
        #pragma unroll
        for (int h = 0; h < HH; ++h) {
            float adj = rs * (logits[h * NN + n] - mean * Gs[h]);
            o[h] = __expf(adj - stats[h]) * stats[8 + h];
        }
        float* op = out + (size_t)n * LL * HH + (size_t)l * HH;
        float4 p0 = {o[0], o[1], o[2], o[3]};
        float4 p1 = {o[4], o[5], o[6], o[7]};
        *(float4*)(op)     = p0;
        *(float4*)(op + 4) = p1;
    }
}

extern "C" void kernel_launch(void* const* d_in, const int* in_sizes, int n_in,
                              void* d_out, int out_size, void* d_ws, size_t ws_size,
                              hipStream_t stream) {
    (void)in_sizes; (void)n_in; (void)out_size; (void)ws_size;
    const float* msa   = (const float*)d_in[0];
    const float* Wq    = (const float*)d_in[1];
    const float* bq    = (const float*)d_in[2];
    const float* Wk    = (const float*)d_in[3];
    // d_in[4] = bk: per-(l,h) const in logits -> cancelled by softmax over n.
    const float* gamma = (const float*)d_in[5];
    const float* beta  = (const float*)d_in[6];
    unsigned short* Wg = (unsigned short*)d_ws;                      // [256][16][256] bf16 = 2 MB
    float* Gsum = (float*)((char*)d_ws + (size_t)2 * 1024 * 1024);   // [256][8] f32
    k_prep<<<dim3(LL), dim3(256), 0, stream>>>(msa, Wq, bq, Wk, gamma, beta, Wg, Gsum);
    k_main<<<dim3(LL), dim3(512), 0, stream>>>(msa, Wg, Gsum, (float*)d_out);
}

// Round 4
// 43.048 us; speedup vs baseline: 1.4000x; 1.2464x over previous
//
#include <hip/hip_runtime.h>
#include <hip/hip_bf16.h>
#include <cstdint>

#define LL 256   // L
#define NN 512   // N
#define DD 256   // D
#define HH 8
#define EPSF 1e-5f
#define WGS 264  // padded LDS row stride (bf16 elems) for Wg

typedef __attribute__((ext_vector_type(8))) __bf16 bf16x8;
typedef __attribute__((ext_vector_type(4))) float f32x4;

static __device__ __forceinline__ void load_group(
    const float* __restrict__ msa, int l, int wave, int col, int kb, int g,
    float4 (&buf)[16])
{
    const float* rp = msa + ((size_t)(g * 128 + (wave << 4) + col) * LL + l) * DD + (kb << 3);
    #pragma unroll
    for (int ks = 0; ks < 8; ++ks) {
        buf[2 * ks]     = *(const float4*)(rp + ks * 32);
        buf[2 * ks + 1] = *(const float4*)(rp + ks * 32 + 4);
    }
}

static __device__ __forceinline__ void compute_group(
    const float4 (&buf)[16], const bf16x8 (&bfr)[8], f32x4& hacc, f32x4& gacc)
{
    #pragma unroll
    for (int ks = 0; ks < 8; ++ks) {
        float4 u = buf[2 * ks], v = buf[2 * ks + 1];
        bf16x8 a;
        a[0] = (__bf16)u.x; a[1] = (__bf16)u.y; a[2] = (__bf16)u.z; a[3] = (__bf16)u.w;
        a[4] = (__bf16)v.x; a[5] = (__bf16)v.y; a[6] = (__bf16)v.z; a[7] = (__bf16)v.w;
        hacc = __builtin_amdgcn_mfma_f32_16x16x32_bf16(a, bfr[ks], hacc, 0, 0, 0);
        gacc = __builtin_amdgcn_mfma_f32_16x16x32_bf16(a, a,       gacc, 0, 0, 0);
    }
}

static __device__ __forceinline__ void store_group(
    int g, int wave, int col, int kb, const f32x4& hacc, const f32x4& gacc,
    float* logits, float* sS, float* sQ)
{
    const int nb = g * 128 + (wave << 4);
    #pragma unroll
    for (int i = 0; i < 4; ++i) {
        int n = nb + (kb << 2) + i;          // C/D: col=lane&15, row=kb*4+i
        if (col < HH)       logits[col * NN + n] = hacc[i];
        else if (col == HH) sS[n] = hacc[i];
    }
    if (kb == (col >> 2)) sQ[nb + col] = gacc[col & 3];   // Gram diagonal
}

__global__ __launch_bounds__(512, 2) void k_fused(
    const float* __restrict__ msa, const float* __restrict__ Wq,
    const float* __restrict__ bq, const float* __restrict__ Wk,
    const float* __restrict__ gamma, const float* __restrict__ beta,
    float* __restrict__ out)
{
    const int l = blockIdx.x;
    const int tid = threadIdx.x, wave = tid >> 6, lane = tid & 63;
    const int col = lane & 15, kb = lane >> 4;

    __shared__ __align__(16) float logits[HH * NN];   // 16 KB
    __shared__ __align__(16) float sS[NN];            // 2 KB   Σx̂ per row
    __shared__ __align__(16) float sQ[NN];            // 2 KB   Σx̂² per row
    __shared__ __align__(16) __bf16 WgL[16 * WGS];    // 8.25 KB
    __shared__ float lnx[DD];
    __shared__ float qv[DD];
    __shared__ float red[8];
    __shared__ float stats[16];
    __shared__ float Gs[HH];

    // ---------- Phase 1: per-l fused weights Wg = gamma ⊙ (q·Wk), in LDS ----------
    {
        float x0 = (tid < DD) ? msa[(size_t)l * DD + tid] : 0.f;
        float s = x0, ss = x0 * x0;
        #pragma unroll
        for (int m = 32; m >= 1; m >>= 1) { s += __shfl_xor(s, m); ss += __shfl_xor(ss, m); }
        if (tid < DD && lane == 0) { red[wave * 2] = s; red[wave * 2 + 1] = ss; }
        __syncthreads();
        if (tid < DD) {
            float sm = red[0] + red[2] + red[4] + red[6];
            float sq = red[1] + red[3] + red[5] + red[7];
            float mean = sm * (1.f / DD);
            float var  = sq * (1.f / DD) - mean * mean;
            float rs   = rsqrtf(var + EPSF);
            lnx[tid] = (x0 - mean) * rs * gamma[tid] + beta[tid];
        }
        __syncthreads();
        // q = (Wq · lnx + bq) * 1/sqrt(DH); each row split across 2 threads
        const int r = tid & 255, hf = tid >> 8;
        float acc = 0.f;
        {
            const float4* wr = (const float4*)(Wq + (size_t)r * DD) + hf * 32;
            const float* lx = lnx + hf * 128;
            #pragma unroll 4
            for (int j = 0; j < 32; ++j) {
                float4 w4 = wr[j];
                acc += lx[4*j] * w4.x + lx[4*j+1] * w4.y + lx[4*j+2] * w4.z + lx[4*j+3] * w4.w;
            }
        }
        if (hf == 0) qv[r] = acc;
        __syncthreads();
        if (hf == 1) qv[r] = (qv[r] + acc + bq[r]) * 0.17677669529663687f;
        __syncthreads();
        // Wg rows: thread handles col c for 4 heads (half-split by tid>>8)
        const int c = tid & 255, h0 = (tid >> 8) * 4;
        #pragma unroll
        for (int hi = 0; hi < 4; ++hi) {
            int h = h0 + hi;
            float a = 0.f;
            const float* wk = Wk + ((size_t)h * 32) * DD + c;
            #pragma unroll 8
            for (int d = 0; d < 32; ++d)
                a += qv[h * 32 + d] * wk[(size_t)d * DD];
            WgL[h * WGS + c] = (__bf16)(gamma[c] * a);
        }
        if (tid < DD) {
            WgL[8 * WGS + tid] = (__bf16)1.0f;     // ones column -> row sums
        } else {
            const int c2 = tid - 256;
            #pragma unroll
            for (int h = 9; h < 16; ++h) WgL[h * WGS + c2] = (__bf16)0.0f;
        }
        __syncthreads();
        if (wave < HH) {                           // G[h] = sum_c Wg[h][c]
            float gsum = 0.f;
            #pragma unroll
            for (int i = 0; i < 4; ++i) gsum += (float)WgL[wave * WGS + lane * 4 + i];
            #pragma unroll
            for (int m = 32; m >= 1; m >>= 1) gsum += __shfl_xor(gsum, m);
            if (lane == 0) Gs[wave] = gsum;
        }
        __syncthreads();
    }

    // ---------- B fragments from LDS ----------
    bf16x8 bfr[8];
    #pragma unroll
    for (int ks = 0; ks < 8; ++ks)
        bfr[ks] = *(const bf16x8*)&WgL[col * WGS + ks * 32 + kb * 8];

    // ---------- Main loop: 4 groups of 16 rows/wave, 2-deep pipelined ----------
    float4 A[16], B[16];
    load_group(msa, l, wave, col, kb, 0, A);
    load_group(msa, l, wave, col, kb, 1, B);
    const f32x4 z = {0.f, 0.f, 0.f, 0.f};
    {
        f32x4 ha = z, ga = z;
        compute_group(A, bfr, ha, ga);
        load_group(msa, l, wave, col, kb, 2, A);
        store_group(0, wave, col, kb, ha, ga, logits, sS, sQ);
    }
    {
        f32x4 ha = z, ga = z;
        compute_group(B, bfr, ha, ga);
        load_group(msa, l, wave, col, kb, 3, B);
        store_group(1, wave, col, kb, ha, ga, logits, sS, sQ);
    }
    {
        f32x4 ha = z, ga = z;
        compute_group(A, bfr, ha, ga);
        store_group(2, wave, col, kb, ha, ga, logits, sS, sQ);
    }
    {
        f32x4 ha = z, ga = z;
        compute_group(B, bfr, ha, ga);
        store_group(3, wave, col, kb, ha, ga, logits, sS, sQ);
    }
    __syncthreads();

    // ---------- softmax stats: wave w -> head h=w ----------
    {
        const int h = wave;
        const float Gh = Gs[h];
        const float* lp = logits + h * NN;
        float4 ra = ((const float4*)lp)[lane * 2];
        float4 rb = ((const float4*)lp)[lane * 2 + 1];
        float4 sa = ((const float4*)sS)[lane * 2];
        float4 sb = ((const float4*)sS)[lane * 2 + 1];
        float4 qa = ((const float4*)sQ)[lane * 2];
        float4 qb = ((const float4*)sQ)[lane * 2 + 1];
        float raw[8] = {ra.x, ra.y, ra.z, ra.w, rb.x, rb.y, rb.z, rb.w};
        float sv[8]  = {sa.x, sa.y, sa.z, sa.w, sb.x, sb.y, sb.z, sb.w};
        float qv2[8] = {qa.x, qa.y, qa.z, qa.w, qb.x, qb.y, qb.z, qb.w};
        float adj[8];
        #pragma unroll
        for (int i = 0; i < 8; ++i) {
            float mean = sv[i] * (1.f / DD);
            float var  = qv2[i] * (1.f / DD) - mean * mean;
            float rs   = rsqrtf(var + EPSF);
            adj[i] = rs * (raw[i] - mean * Gh);
        }
        float mx = adj[0];
        #pragma unroll
        for (int i = 1; i < 8; ++i) mx = fmaxf(mx, adj[i]);
        #pragma unroll
        for (int m = 32; m >= 1; m >>= 1) mx = fmaxf(mx, __shfl_xor(mx, m));
        float sm = 0.f;
        #pragma unroll
        for (int i = 0; i < 8; ++i) sm += __expf(adj[i] - mx);
        #pragma unroll
        for (int m = 32; m >= 1; m >>= 1) sm += __shfl_xor(sm, m);
        if (lane == 0) { stats[wave] = mx; stats[8 + wave] = 1.f / sm; }
    }
    __syncthreads();

    // ---------- epilogue: thread t -> n=t, 8 heads, fp32 out ----------
    {
        const int n = tid;
        float s = sS[n], q2 = sQ[n];
        float mean = s * (1.f / DD);
        float var  = q2 * (1.f / DD) - mean * mean;
        float rs   = rsqrtf(var + EPSF);
        float o[8];
        #pragma unroll
        for (int h = 0; h < HH; ++h) {
            float adj = rs * (logits[h * NN + n] - mean * Gs[h]);
            o[h] = __expf(adj - stats[h]) * stats[8 + h];
        }
        float* op = out + (size_t)n * LL * HH + (size_t)l * HH;
        float4 p0 = {o[0], o[1], o[2], o[3]};
        float4 p1 = {o[4], o[5], o[6], o[7]};
        *(float4*)(op)     = p0;
        *(float4*)(op + 4) = p1;
    }
}

extern "C" void kernel_launch(void* const* d_in, const int* in_sizes, int n_in,
                              void* d_out, int out_size, void* d_ws, size_t ws_size,
                              hipStream_t stream) {
    (void)in_sizes; (void)n_in; (void)out_size; (void)d_ws; (void)ws_size;
    const float* msa   = (const float*)d_in[0];
    const float* Wq    = (const float*)d_in[1];
    const float* bq    = (const float*)d_in[2];
    const float* Wk    = (const float*)d_in[3];
    // d_in[4] = bk: per-(l,h) constant in logits -> cancelled by softmax over n.
    const float* gamma = (const float*)d_in[5];
    const float* beta  = (const float*)d_in[6];
    k_fused<<<dim3(LL), dim3(512), 0, stream>>>(msa, Wq, bq, Wk, gamma, beta, (float*)d_out);
}